// Round 5
// baseline (242.819 us; speedup 1.0000x reference)
//
#include <hip/hip_runtime.h>
#include <hip/hip_bf16.h>
#include <float.h>

#define NTOK   2048
#define VOCAB  32000
#define DIM    512
#define NCHUNK 128
#define NTILES 2000               // 16-row vocab tiles
#define ROWSB  128                // rows per block (4 waves x 32 rows)
#define NRB    (NTOK / ROWSB)     // 16
#define TILE_BYTES 16384          // 16 rows x 512 k x 2B, fragment-linear image

typedef __attribute__((ext_vector_type(4))) float  f32x4;
typedef __attribute__((ext_vector_type(8))) short  bf16x8;

__device__ __forceinline__ short f2bf(float f) {
    unsigned u = __builtin_bit_cast(unsigned, f);
    u = (u + 0x7FFFu + ((u >> 16) & 1u)) >> 16;   // RNE to bf16
    return (short)u;
}

__device__ __forceinline__ bf16x8 cvt8(f32x4 a, f32x4 b) {
    bf16x8 r;
    r[0]=f2bf(a.x); r[1]=f2bf(a.y); r[2]=f2bf(a.z); r[3]=f2bf(a.w);
    r[4]=f2bf(b.x); r[5]=f2bf(b.y); r[6]=f2bf(b.z); r[7]=f2bf(b.w);
    return r;
}

__global__ void init_out(float* out) {
    if (threadIdx.x < 2) out[threadIdx.x] = 0.f;
}

// ---- precast: emb fp32 -> bf16 FRAGMENT-LINEAR image + e2, one pass ----
// frag(tile, ks, lane) at byte tile*16384 + ks*1024 + lane*16 holds
// B[v0 + (lane&15)][ks*32 + (lane>>4)*8 + j], j=0..7.
// Wave-per-row: lane l holds k = l*8.. -> ks = l>>2, lg = l&3, out-lane = lg*16+v.
__global__ __launch_bounds__(256) void precast_kernel(
    const float* __restrict__ emb, short* __restrict__ Bbf, float* __restrict__ e2) {
    const int tile = blockIdx.x;
    const int t = threadIdx.x, w = t >> 6, l = t & 63;
    const int v0 = tile * 16;
    char* tbase = (char*)Bbf + (size_t)tile * TILE_BYTES;
    #pragma unroll
    for (int it = 0; it < 4; ++it) {
        const int v = it * 4 + w;
        const float* src = emb + (size_t)(v0 + v) * DIM + l * 8;
        f32x4 x0 = *(const f32x4*)src;
        f32x4 x1 = *(const f32x4*)(src + 4);
        float sq = x0.x*x0.x + x0.y*x0.y + x0.z*x0.z + x0.w*x0.w
                 + x1.x*x1.x + x1.y*x1.y + x1.z*x1.z + x1.w*x1.w;
        #pragma unroll
        for (int m = 1; m < 64; m <<= 1) sq += __shfl_xor(sq, m);
        if (l == 0) e2[v0 + v] = sq;
        char* dst = tbase + (l >> 2) * 1024 + (((l & 3) * 16 + v) * 16);
        *(bf16x8*)dst = cvt8(x0, x1);
    }
}

// e2-only fallback
__global__ __launch_bounds__(256) void e2_kernel(const float* __restrict__ emb,
                                                 float* __restrict__ e2) {
    int gid = blockIdx.x * 256 + threadIdx.x;
    int wid = gid >> 6, l = gid & 63;
    if (wid >= VOCAB) return;
    const float* row = emb + (size_t)wid * DIM + l * 8;
    f32x4 a = *(const f32x4*)row;
    f32x4 b = *(const f32x4*)(row + 4);
    float s = a.x*a.x + a.y*a.y + a.z*a.z + a.w*a.w
            + b.x*b.x + b.y*b.y + b.z*b.z + b.w*b.w;
    #pragma unroll
    for (int m = 1; m < 64; m <<= 1) s += __shfl_xor(s, m);
    if (l == 0) e2[wid] = s;
}

// ---- fused: NO LDS, NO syncthreads; B-frags direct from fragment-linear
// image (contiguous 1KB per wave-instr); rotating quarter-tile reg dbuf ----
template<bool PRECAST>
__global__ __launch_bounds__(256, 2) void fused_kernel(
    const float* __restrict__ pred_ll, const int* __restrict__ target,
    const float* __restrict__ emb, const short* __restrict__ Bbf,
    const float* __restrict__ e2g,
    float* __restrict__ partials /* [NTOK][NCHUNK][2] */) {

    const int rb = blockIdx.x;
    const int ch = blockIdx.y;
    const int t  = threadIdx.x;
    const int l  = t & 63;
    const int l15 = l & 15;
    const int lg  = l >> 4;               // 0..3
    const int w   = t >> 6;               // 0..3

    const int t0 = (ch * NTILES) >> 7;
    const int t1 = ((ch + 1) * NTILES) >> 7;
    const int rowbase = rb * ROWSB + w * 32;

    // A fragments: 32 gold rows per wave (2 sets of 16)
    bf16x8 afrag[2][16];
    #pragma unroll
    for (int s = 0; s < 2; ++s) {
        const int grow = target[rowbase + s * 16 + l15];
        if constexpr (PRECAST) {
            const char* ab = (const char*)Bbf + (size_t)(grow >> 4) * TILE_BYTES
                           + ((l & 48) + (grow & 15)) * 16;
            #pragma unroll
            for (int ks = 0; ks < 16; ++ks)
                afrag[s][ks] = *(const bf16x8*)(ab + ks * 1024);
        } else {
            const float* gsrc = emb + (size_t)grow * DIM;
            #pragma unroll
            for (int ks = 0; ks < 16; ++ks) {
                const int k0 = ks * 32 + lg * 8;
                afrag[s][ks] = cvt8(*(const f32x4*)(gsrc + k0),
                                    *(const f32x4*)(gsrc + k0 + 4));
            }
        }
    }
    float g2[2][4];
    #pragma unroll
    for (int s = 0; s < 2; ++s)
        #pragma unroll
        for (int r = 0; r < 4; ++r)
            g2[s][r] = e2g[target[rowbase + s * 16 + lg * 4 + r]];

    float s_[2][4] = {{0,0,0,0},{0,0,0,0}};
    float ac_[2][4] = {{0,0,0,0},{0,0,0,0}};

    auto loadq = [&](int tg, int qp, bf16x8* dst) {
        if constexpr (PRECAST) {
            const char* src = (const char*)Bbf + (size_t)tg * TILE_BYTES
                            + qp * 4096 + l * 16;
            #pragma unroll
            for (int k = 0; k < 4; ++k)
                dst[k] = *(const bf16x8*)(src + k * 1024);
        } else {
            const float* bsrc = emb + (size_t)(tg * 16 + l15) * DIM;
            #pragma unroll
            for (int k = 0; k < 4; ++k) {
                const int k0 = (qp * 4 + k) * 32 + lg * 8;
                dst[k] = cvt8(*(const f32x4*)(bsrc + k0),
                              *(const f32x4*)(bsrc + k0 + 4));
            }
        }
    };

    bf16x8 buf[2][4];
    loadq(t0, 0, buf[0]);

    #pragma unroll 1
    for (int tg = t0; tg < t1; ++tg) {
        const int v0 = tg * 16;
        const float e2v = e2g[v0 + l15];
        float q[2][4];
        {
            const size_t p0 = (size_t)rowbase * VOCAB + v0 + l15;
            #pragma unroll
            for (int s = 0; s < 2; ++s)
                #pragma unroll
                for (int r = 0; r < 4; ++r)
                    q[s][r] = pred_ll[p0 + (size_t)(s * 16 + lg * 4 + r) * VOCAB];
        }

        f32x4 accs[2] = {{0,0,0,0},{0,0,0,0}};
        #pragma unroll
        for (int qp = 0; qp < 4; ++qp) {
            const int ntg = (qp == 3) ? ((tg + 1 < t1) ? tg + 1 : tg) : tg;
            const int nqp = (qp + 1) & 3;
            loadq(ntg, nqp, buf[(qp + 1) & 1]);
            #pragma unroll
            for (int k = 0; k < 4; ++k) {
                accs[0] = __builtin_amdgcn_mfma_f32_16x16x32_bf16(
                    afrag[0][qp * 4 + k], buf[qp & 1][k], accs[0], 0, 0, 0);
                accs[1] = __builtin_amdgcn_mfma_f32_16x16x32_bf16(
                    afrag[1][qp * 4 + k], buf[qp & 1][k], accs[1], 0, 0, 0);
            }
        }

        #pragma unroll
        for (int s = 0; s < 2; ++s)
            #pragma unroll
            for (int r = 0; r < 4; ++r) {
                float d2 = fmaxf(fmaf(-2.f, accs[s][r], g2[s][r] + e2v), 1e-12f);
                const float e = __expf(-sqrtf(d2));
                s_[s][r] += e;
                ac_[s][r] = fmaf(e, -q[s][r], ac_[s][r]);
            }

        // re-converge waves every 4 tiles for L1 tile locality (bare barrier:
        // nothing is shared, no memory semantics needed)
        if (((tg - t0) & 3) == 3) __builtin_amdgcn_s_barrier();
    }

    #pragma unroll
    for (int s = 0; s < 2; ++s)
        #pragma unroll
        for (int r = 0; r < 4; ++r) {
            float sv = s_[s][r], av = ac_[s][r];
            #pragma unroll
            for (int m = 1; m < 16; m <<= 1) {
                sv += __shfl_xor(sv, m);
                av += __shfl_xor(av, m);
            }
            if (l15 == 0) {
                const int rg = rowbase + s * 16 + lg * 4 + r;
                float* pp = partials + ((size_t)rg * NCHUNK + ch) * 2;
                pp[0] = sv; pp[1] = av;
            }
        }
}

__global__ __launch_bounds__(256) void reduce_kernel(
    const float* __restrict__ pred_ll, const int* __restrict__ target,
    const float* __restrict__ partials, float* __restrict__ out) {
    const int row = blockIdx.x * 256 + threadIdx.x;
    float loss = 0.f, nll = 0.f;
    if (row < NTOK) {
        const int tg = target[row];
        const float mask = (tg != 0) ? 1.f : 0.f;
        const float* pp = partials + (size_t)row * NCHUNK * 2;
        float S = 0.f, A = 0.f;
        #pragma unroll 8
        for (int c = 0; c < NCHUNK; ++c) { S += pp[c * 2]; A += pp[c * 2 + 1]; }
        loss = mask * (A / S);
        nll  = mask * (-pred_ll[(size_t)row * VOCAB + tg]);
    }
    #pragma unroll
    for (int o = 32; o > 0; o >>= 1) {
        loss += __shfl_xor(loss, o);
        nll  += __shfl_xor(nll, o);
    }
    if ((threadIdx.x & 63) == 0) {
        atomicAdd(&out[0], loss);
        atomicAdd(&out[1], nll);
    }
}

extern "C" void kernel_launch(void* const* d_in, const int* in_sizes, int n_in,
                              void* d_out, int out_size, void* d_ws, size_t ws_size,
                              hipStream_t stream) {
    const float* pred_ll = (const float*)d_in[0];
    const int*   target  = (const int*)d_in[1];
    const float* emb     = (const float*)d_in[2];
    float* out = (float*)d_out;

    // ws layout: [e2: VOCAB f32][partials: NTOK*NCHUNK*2 f32][Bbf image]
    float* e2       = (float*)d_ws;
    float* partials = e2 + VOCAB;
    const size_t base = (size_t)VOCAB * 4 + (size_t)NTOK * NCHUNK * 2 * 4;
    short* Bbf      = (short*)((char*)d_ws + base);
    const size_t need = base + (size_t)NTILES * TILE_BYTES;
    const bool precast = (ws_size >= need);

    hipLaunchKernelGGL(init_out, dim3(1), dim3(64), 0, stream, out);
    if (precast) {
        hipLaunchKernelGGL(precast_kernel, dim3(NTILES), dim3(256), 0, stream, emb, Bbf, e2);
        hipLaunchKernelGGL((fused_kernel<true>), dim3(NRB, NCHUNK), dim3(256), 0, stream,
                           pred_ll, target, emb, Bbf, e2, partials);
    } else {
        hipLaunchKernelGGL(e2_kernel, dim3(VOCAB * 64 / 256), dim3(256), 0, stream, emb, e2);
        hipLaunchKernelGGL((fused_kernel<false>), dim3(NRB, NCHUNK), dim3(256), 0, stream,
                           pred_ll, target, emb, Bbf, e2, partials);
    }
    hipLaunchKernelGGL(reduce_kernel, dim3(NTOK / 256), dim3(256), 0, stream,
                       pred_ll, target, partials, out);
}

// Round 6
// 151.090 us; speedup vs baseline: 1.6071x; 1.6071x over previous
//
#include <hip/hip_runtime.h>
#include <float.h>

#define NTOK   2048
#define VOCAB  32000
#define DIM    512
#define NCHUNK 32
#define NTILES 2000               // 16-col vocab tiles
#define ROWSB  64                 // rows per block (4 waves x 16 rows)
#define NRB    (NTOK / ROWSB)     // 32
#define TILE_BYTES 8192           // 16 cols x 512 k x 1B fp8, fragment-linear

typedef __attribute__((ext_vector_type(4))) float f32x4;
typedef unsigned int u32;
typedef long long i64;

// pack 8 consecutive fp32 (k..k+7) into 8 fp8-e4m3 bytes (k-order = byte order)
__device__ __forceinline__ i64 pack_fp8x8(f32x4 x0, f32x4 x1) {
    int lo = __builtin_amdgcn_cvt_pk_fp8_f32(x0.x, x0.y, 0, false);
    lo = __builtin_amdgcn_cvt_pk_fp8_f32(x0.z, x0.w, lo, true);
    int hi = __builtin_amdgcn_cvt_pk_fp8_f32(x1.x, x1.y, 0, false);
    hi = __builtin_amdgcn_cvt_pk_fp8_f32(x1.z, x1.w, hi, true);
    return (i64)(((unsigned long long)(u32)hi << 32) | (u32)lo);
}

__device__ __forceinline__ void async_copy16(void* lds, const void* g) {
    __builtin_amdgcn_global_load_lds(
        (const __attribute__((address_space(1))) u32*)(const u32*)g,
        (__attribute__((address_space(3))) u32*)(u32*)lds, 16, 0, 0);
}

__global__ void init_out(float* out) {
    if (threadIdx.x < 2) out[threadIdx.x] = 0.f;
}

// ---- precast: emb fp32 -> fp8 FRAGMENT-LINEAR image + e2 (fp32), one pass ----
// frag(tile, ks, il) at byte tile*8192 + ks*512 + il*8 holds
// B[v0 + (il&15)][ks*32 + (il>>4)*8 + j], j=0..7 (one i64 per image-lane).
// Wave-per-row: lane l holds k = l*8..l*8+7 -> ks = l>>2, il = (l&3)*16 + v.
__global__ __launch_bounds__(256) void precast_kernel(
    const float* __restrict__ emb, char* __restrict__ Bbf, float* __restrict__ e2) {
    const int tile = blockIdx.x;
    const int t = threadIdx.x, w = t >> 6, l = t & 63;
    const int v0 = tile * 16;
    char* tbase = Bbf + (size_t)tile * TILE_BYTES;
    #pragma unroll
    for (int it = 0; it < 4; ++it) {
        const int v = it * 4 + w;
        const float* src = emb + (size_t)(v0 + v) * DIM + l * 8;
        f32x4 x0 = *(const f32x4*)src;
        f32x4 x1 = *(const f32x4*)(src + 4);
        float sq = x0.x*x0.x + x0.y*x0.y + x0.z*x0.z + x0.w*x0.w
                 + x1.x*x1.x + x1.y*x1.y + x1.z*x1.z + x1.w*x1.w;
        #pragma unroll
        for (int m = 1; m < 64; m <<= 1) sq += __shfl_xor(sq, m);
        if (l == 0) e2[v0 + v] = sq;
        *(i64*)(tbase + (l >> 2) * 512 + ((l & 3) * 16 + v) * 8) = pack_fp8x8(x0, x1);
    }
}

// e2-only fallback
__global__ __launch_bounds__(256) void e2_kernel(const float* __restrict__ emb,
                                                 float* __restrict__ e2) {
    int gid = blockIdx.x * 256 + threadIdx.x;
    int wid = gid >> 6, l = gid & 63;
    if (wid >= VOCAB) return;
    const float* row = emb + (size_t)wid * DIM + l * 8;
    f32x4 a = *(const f32x4*)row;
    f32x4 b = *(const f32x4*)(row + 4);
    float s = a.x*a.x + a.y*a.y + a.z*a.z + a.w*a.w
            + b.x*b.x + b.y*b.y + b.z*b.z + b.w*b.w;
    #pragma unroll
    for (int m = 1; m < 64; m <<= 1) s += __shfl_xor(s, m);
    if (l == 0) e2[wid] = s;
}

// ---- fused: fp8 MFMA, 4 waves x 16 rows, 4 blocks/CU co-resident,
// double-buffered 8KB LDS B-tile, counted-vmcnt across barrier ----
template<bool PRECAST>
__global__ __launch_bounds__(256, 4) void fused_kernel(
    const float* __restrict__ pred_ll, const int* __restrict__ target,
    const float* __restrict__ emb, const char* __restrict__ Bbf,
    const float* __restrict__ e2g,
    float* __restrict__ partials /* [NTOK][NCHUNK][2] */) {

    const int rb = blockIdx.x;
    const int ch = blockIdx.y;
    const int t  = threadIdx.x;
    const int w  = t >> 6;                // 0..3
    const int l  = t & 63;
    const int l15 = l & 15;
    const int lg  = l >> 4;               // 0..3

    __shared__ char ldsB[2][TILE_BYTES];

    const int t0 = (ch * NTILES) >> 5;
    const int t1 = ((ch + 1) * NTILES) >> 5;
    const int rowbase = rb * ROWSB + w * 16;

    // A fragments: 16 gold rows per wave, fp8, 32 VGPRs
    i64 afrag[16];
    {
        const int grow = target[rowbase + l15];
        if constexpr (PRECAST) {
            const char* ab = Bbf + (size_t)(grow >> 4) * TILE_BYTES
                           + ((l & 48) + (grow & 15)) * 8;
            #pragma unroll
            for (int ks = 0; ks < 16; ++ks)
                afrag[ks] = *(const i64*)(ab + ks * 512);
        } else {
            const float* gsrc = emb + (size_t)grow * DIM;
            #pragma unroll
            for (int ks = 0; ks < 16; ++ks) {
                const int k0 = ks * 32 + ((l >> 4) << 3);
                afrag[ks] = pack_fp8x8(*(const f32x4*)(gsrc + k0),
                                       *(const f32x4*)(gsrc + k0 + 4));
            }
        }
    }
    float g2[4];
    #pragma unroll
    for (int r = 0; r < 4; ++r) g2[r] = e2g[target[rowbase + lg * 4 + r]];

    float s_[4] = {0.f, 0.f, 0.f, 0.f};
    float ac_[4] = {0.f, 0.f, 0.f, 0.f};

    auto stage = [&](int buf, int tg) {
        if constexpr (PRECAST) {
            const char* src = Bbf + (size_t)tg * TILE_BYTES;
            async_copy16(ldsB[buf] + t * 16, src + t * 16);
            async_copy16(ldsB[buf] + 4096 + t * 16, src + 4096 + t * 16);
        } else {
            const int v0 = tg * 16;
            #pragma unroll
            for (int it = 0; it < 4; ++it) {
                const int c = it * 256 + t;        // 1024 image-lanes of 8B
                const int ks = c >> 6, il = c & 63;
                const int v = il & 15, k0 = ks * 32 + ((il >> 4) << 3);
                const float* src = emb + (size_t)(v0 + v) * DIM + k0;
                *(i64*)(ldsB[buf] + ks * 512 + il * 8) =
                    pack_fp8x8(*(const f32x4*)src, *(const f32x4*)(src + 4));
            }
        }
    };

    stage(0, t0);

    int cur = 0;
    #pragma unroll 1
    for (int tg = t0; tg < t1; ++tg) {
        if (tg + 1 < t1) {
            stage(cur ^ 1, tg + 1);
            if constexpr (PRECAST)
                asm volatile("s_waitcnt vmcnt(2)" ::: "memory");   // prev tile done; 2 new in flight
            else
                asm volatile("s_waitcnt vmcnt(0) lgkmcnt(0)" ::: "memory");
        } else {
            asm volatile("s_waitcnt vmcnt(0) lgkmcnt(0)" ::: "memory");
        }
        __builtin_amdgcn_s_barrier();

        const int v0 = tg * 16;
        const float e2v = e2g[v0 + l15];
        float q[4];
        {
            const size_t p0 = (size_t)rowbase * VOCAB + v0 + l15;
            #pragma unroll
            for (int r = 0; r < 4; ++r)
                q[r] = pred_ll[p0 + (size_t)(lg * 4 + r) * VOCAB];
        }

        // MFMA: 16 rows x 16 cols, K=512, fp8
        f32x4 acc = {0.f, 0.f, 0.f, 0.f};
        const char* lb = ldsB[cur];
        #pragma unroll
        for (int ks = 0; ks < 16; ++ks) {
            const i64 b = *(const i64*)(lb + ks * 512 + l * 8);
            acc = __builtin_amdgcn_mfma_f32_16x16x32_fp8_fp8(afrag[ks], b, acc, 0, 0, 0);
        }

        // epilogue: dist -> exp(-dist) (fixed max = 0: dist >= 0, exact)
        #pragma unroll
        for (int r = 0; r < 4; ++r) {
            float d2 = fmaxf(fmaf(-2.f, acc[r], g2[r] + e2v), 1e-12f);
            const float e = __expf(-sqrtf(d2));
            s_[r] += e;
            ac_[r] = fmaf(e, -q[r], ac_[r]);
        }

        asm volatile("" ::: "memory");
        __builtin_amdgcn_s_barrier();    // all reads of cur done before overwrite
        cur ^= 1;
    }

    // combine 16 col-slices within each 16-lane group
    #pragma unroll
    for (int r = 0; r < 4; ++r) {
        float sv = s_[r], av = ac_[r];
        #pragma unroll
        for (int m = 1; m < 16; m <<= 1) {
            sv += __shfl_xor(sv, m);
            av += __shfl_xor(av, m);
        }
        if (l15 == 0) {
            const int rg = rowbase + lg * 4 + r;
            float* pp = partials + ((size_t)rg * NCHUNK + ch) * 2;
            pp[0] = sv; pp[1] = av;
        }
    }
}

__global__ __launch_bounds__(256) void reduce_kernel(
    const float* __restrict__ pred_ll, const int* __restrict__ target,
    const float* __restrict__ partials, float* __restrict__ out) {
    const int row = blockIdx.x * 256 + threadIdx.x;
    float loss = 0.f, nll = 0.f;
    if (row < NTOK) {
        const int tg = target[row];
        const float mask = (tg != 0) ? 1.f : 0.f;
        const float* pp = partials + (size_t)row * NCHUNK * 2;
        float S = 0.f, A = 0.f;
        #pragma unroll 8
        for (int c = 0; c < NCHUNK; ++c) { S += pp[c * 2]; A += pp[c * 2 + 1]; }
        loss = mask * (A / S);
        nll  = mask * (-pred_ll[(size_t)row * VOCAB + tg]);
    }
    #pragma unroll
    for (int o = 32; o > 0; o >>= 1) {
        loss += __shfl_xor(loss, o);
        nll  += __shfl_xor(nll, o);
    }
    if ((threadIdx.x & 63) == 0) {
        atomicAdd(&out[0], loss);
        atomicAdd(&out[1], nll);
    }
}

extern "C" void kernel_launch(void* const* d_in, const int* in_sizes, int n_in,
                              void* d_out, int out_size, void* d_ws, size_t ws_size,
                              hipStream_t stream) {
    const float* pred_ll = (const float*)d_in[0];
    const int*   target  = (const int*)d_in[1];
    const float* emb     = (const float*)d_in[2];
    float* out = (float*)d_out;

    // ws layout: [e2: VOCAB f32][partials: NTOK*NCHUNK*2 f32][fp8 image ~16MB]
    float* e2       = (float*)d_ws;
    float* partials = e2 + VOCAB;
    const size_t base = (size_t)VOCAB * 4 + (size_t)NTOK * NCHUNK * 2 * 4;
    char* Bbf       = (char*)d_ws + base;
    const size_t need = base + (size_t)NTILES * TILE_BYTES;
    const bool precast = (ws_size >= need);

    hipLaunchKernelGGL(init_out, dim3(1), dim3(64), 0, stream, out);
    if (precast) {
        hipLaunchKernelGGL(precast_kernel, dim3(NTILES), dim3(256), 0, stream, emb, Bbf, e2);
        hipLaunchKernelGGL((fused_kernel<true>), dim3(NRB, NCHUNK), dim3(256), 0, stream,
                           pred_ll, target, emb, Bbf, e2, partials);
    } else {
        hipLaunchKernelGGL(e2_kernel, dim3(VOCAB * 64 / 256), dim3(256), 0, stream, emb, e2);
        hipLaunchKernelGGL((fused_kernel<false>), dim3(NRB, NCHUNK), dim3(256), 0, stream,
                           pred_ll, target, emb, Bbf, e2, partials);
    }
    hipLaunchKernelGGL(reduce_kernel, dim3(NTOK / 256), dim3(256), 0, stream,
                       pred_ll, target, partials, out);
}